// Round 1
// 186.949 us; speedup vs baseline: 1.0910x; 1.0910x over previous
//
#include <hip/hip_runtime.h>
#include <cstdint>
#include <cstddef>

#define NIMG 256
#define PADW 18
#define XB_IMG (PADW * PADW * 256)   // 82944 elements per image
#define W2_ROW 2304                  // 9*256

typedef __bf16 bf16x8 __attribute__((ext_vector_type(8)));
typedef float floatx4 __attribute__((ext_vector_type(4)));
typedef float floatvec4 __attribute__((ext_vector_type(4)));

__device__ __forceinline__ unsigned short f2bf(float f) {
    unsigned u = __float_as_uint(f);
    u = (u + 0x7FFFu + ((u >> 16) & 1u)) >> 16;   // RNE
    return (unsigned short)u;
}

__device__ __forceinline__ void gload_lds16(const void* g, void* l) {
    __builtin_amdgcn_global_load_lds(
        (const __attribute__((address_space(1))) void*)g,
        (__attribute__((address_space(3))) void*)l, 16, 0, 0);
}

// counted waits: never drain vmcnt to 0 in the main loop (T4).
// lgkmcnt(0) added so every wave's ds_reads are retired before it enters the
// barrier (closes the theoretical sunk-MFMA read-vs-DMA-write window).
#define VMCNT_LGKM0(n) asm volatile("s_waitcnt vmcnt(" #n ") lgkmcnt(0)" ::: "memory")

// ---------------------------------------------------------------------------
// prep_kernel: merged convert (blocks 0..1023) + wprep (blocks 1024..1167).
// Bodies identical to the previously-verified convert_kernel / wprep_kernel;
// only the blockIdx decode changed. LDS overlaid (34304 B >= 16448 B).
// ---------------------------------------------------------------------------
__global__ __launch_bounds__(256) void prep_kernel(
        const float* __restrict__ x, unsigned short* __restrict__ xb,
        const float* __restrict__ wt, const float* __restrict__ alphas,
        unsigned short* __restrict__ w2) {
    __shared__ __align__(16) char lds_pool[64 * 268 * 2];
    const int bx = blockIdx.x;
    const int t  = threadIdx.x;

    if (bx < 1024) {
        // ---- convert path: x NCHW fp32 -> xb[n][py][px][c] bf16, halo zeroed
        unsigned short (*tile2)[268] = (unsigned short (*)[268])lds_pool;
        const int n  = bx & 255;
        const int cy = bx >> 8;
        const int c0 = cy * 64;
        const float* xi = x + (size_t)n * 65536;
        unsigned short* xo = xb + (size_t)n * XB_IMG;

        if (cy == 0) {
            #pragma unroll
            for (int it = 0; it < 17; ++it) {
                int idx = it * 256 + t;
                int hp = idx >> 6;
                int c4 = (idx & 63) * 4;
                int py, px;
                if (hp < 18)      { py = 0;       px = hp;      }
                else if (hp < 36) { py = 17;      px = hp - 18; }
                else if (hp < 52) { py = hp - 35; px = 0;       }
                else              { py = hp - 51; px = 17;      }
                *(uint2*)&xo[(py * 18 + px) * 256 + c4] = make_uint2(0u, 0u);
            }
        }
        {
            const int p4 = (t & 63) * 4;
            const int ci = t >> 6;
            #pragma unroll
            for (int i = 0; i < 16; ++i) {
                const int c = i * 4 + ci;
                floatvec4 v = *(const floatvec4*)&xi[(c0 + c) * 256 + p4];
                unsigned lo = (unsigned)f2bf(v.x) | ((unsigned)f2bf(v.y) << 16);
                unsigned hi = (unsigned)f2bf(v.z) | ((unsigned)f2bf(v.w) << 16);
                *(uint2*)&tile2[c][p4] = make_uint2(lo, hi);
            }
        }
        __syncthreads();
        #pragma unroll
        for (int it = 0; it < 32; ++it) {
            int idx = it * 256 + t;
            int p   = idx >> 5;
            int cp  = (idx & 31) * 2;
            unsigned lo = tile2[cp][p];
            unsigned hi = tile2[cp + 1][p];
            int py = (p >> 4) + 1, px = (p & 15) + 1;
            *(unsigned int*)&xo[(py * 18 + px) * 256 + c0 + cp] = lo | (hi << 16);
        }
    } else {
        // ---- wprep path: combined circulant weight w2[kout][pos*256+c] bf16
        float (*wlds)[257] = (float (*)[257])lds_pool;
        const int w   = bx - 1024;
        const int o16 = (w & 15) * 16;
        const int pos = w >> 4;

        #pragma unroll
        for (int j = 0; j < 16; ++j)
            wlds[j][t] = wt[((o16 + j) * 256 + t) * 9 + pos];

        float a[5];
        {
            float mx = alphas[0];
            #pragma unroll
            for (int i = 1; i < 5; ++i) mx = fmaxf(mx, alphas[i]);
            float s = 0.f;
            #pragma unroll
            for (int i = 0; i < 5; ++i) { a[i] = __expf(alphas[i] - mx); s += a[i]; }
            float inv = 1.f / s;
            #pragma unroll
            for (int i = 0; i < 5; ++i) a[i] *= inv;
        }
        __syncthreads();

        const int c = t;
        #pragma unroll
        for (int oo = 0; oo < 16; ++oo) {
            float acc = a[0] * wlds[oo][c];
            #pragma unroll
            for (int bi = 0; bi < 4; ++bi) {
                const int b  = 2 << bi;            // 2,4,8,16
                const int r  = oo & (b - 1);
                const int cc = c & (b - 1);
                const int i0 = (r - cc) & (b - 1);
                const int ob = oo - r;
                const int icb = c - cc;
                float s2 = 0.f;
                for (int j = 0; j < b; ++j)
                    s2 += wlds[ob + j][icb + ((j + i0) & (b - 1))];
                acc += a[1 + bi] * s2 * (1.f / (float)b);
            }
            w2[(size_t)(o16 + oo) * W2_ROW + pos * 256 + c] = f2bf(acc);
        }
    }
}

// standalone wprep kept only for the small-workspace fallback path
__global__ __launch_bounds__(256) void wprep_kernel(
        const float* __restrict__ wt, const float* __restrict__ alphas,
        unsigned short* __restrict__ w2) {
    __shared__ float wlds[16][257];
    const int o16 = blockIdx.x * 16;
    const int pos = blockIdx.y;
    const int t   = threadIdx.x;
    #pragma unroll
    for (int j = 0; j < 16; ++j)
        wlds[j][t] = wt[((o16 + j) * 256 + t) * 9 + pos];
    float a[5];
    {
        float mx = alphas[0];
        #pragma unroll
        for (int i = 1; i < 5; ++i) mx = fmaxf(mx, alphas[i]);
        float s = 0.f;
        #pragma unroll
        for (int i = 0; i < 5; ++i) { a[i] = __expf(alphas[i] - mx); s += a[i]; }
        float inv = 1.f / s;
        #pragma unroll
        for (int i = 0; i < 5; ++i) a[i] *= inv;
    }
    __syncthreads();
    const int c = t;
    #pragma unroll
    for (int oo = 0; oo < 16; ++oo) {
        float acc = a[0] * wlds[oo][c];
        #pragma unroll
        for (int bi = 0; bi < 4; ++bi) {
            const int b  = 2 << bi;
            const int r  = oo & (b - 1);
            const int cc = c & (b - 1);
            const int i0 = (r - cc) & (b - 1);
            const int ob = oo - r;
            const int icb = c - cc;
            float s2 = 0.f;
            for (int j = 0; j < b; ++j)
                s2 += wlds[ob + j][icb + ((j + i0) & (b - 1))];
            acc += a[1 + bi] * s2 * (1.f / (float)b);
        }
        w2[(size_t)(o16 + oo) * W2_ROW + pos * 256 + c] = f2bf(acc);
    }
}

// ---------------------------------------------------------------------------
// gemm_kernel v6: 256x256 tile per block (1 block = 1 image, grid=256=1/CU),
// 512 threads = 8 waves (2M x 4N), per-wave 128x64 output, BK=32 half-steps
// (72 of them), ring-4 LDS half-buffers per operand (128 KB, dynamic),
// stage 3 batches ahead, counted s_waitcnt vmcnt(8) + raw s_barrier
// (T3+T4), s_setprio around the 32-MFMA cluster (T5).
//
// LDS layout per half-buffer: 256 rows x 32 bf16 cols (64 B rows).
// Swizzle: phys 8-elt slot = (k_slot + (row>>1)) & 3 -> wave-wide b128 reads
// hit all 32 banks at the 8-cycle minimum. Applied on the global SOURCE
// address (linear global_load_lds dest) and on the ds_read address.
// ---------------------------------------------------------------------------
__global__ __launch_bounds__(512, 2) void gemm_kernel(
        const unsigned short* __restrict__ xb,
        const unsigned short* __restrict__ w2,
        float* __restrict__ out) {
    extern __shared__ __align__(16) char smem[];
    unsigned short* const xs = (unsigned short*)smem;            // 4 x 8192 elems (B: pixels)
    unsigned short* const ws = (unsigned short*)(smem + 65536);  // 4 x 8192 elems (A: kout)

    const int t     = threadIdx.x;
    const int lane  = t & 63;
    const int wid   = t >> 6;
    const int n_img = blockIdx.x;

    // ---- staging setup: waves 0-3 stage XS (pixels), waves 4-7 stage WS ----
    // per gload: wave writes 1024 B = 16 rows; lane -> row=lane>>2, slot=lane&3
    const int q     = lane >> 2;
    const int kswz  = ((lane & 3) - ((lane >> 3) & 3)) & 3;  // source k-slot for phys slot lane&3
    const int choff = kswz * 8;
    const unsigned short* sbase;
    int sg[4];
    int ldst;
    if (wid < 4) {
        sbase = xb;
        #pragma unroll
        for (int i = 0; i < 4; ++i) {
            const int r = wid * 64 + i * 16 + q;       // pixel 0..255
            const int y = r >> 4, xx = r & 15;
            sg[i] = n_img * XB_IMG + ((y + 1) * 18 + (xx + 1)) * 256 + choff;
        }
        ldst = wid * 4096;                             // byte offset in buffer
    } else {
        sbase = w2;
        const int wv = wid - 4;
        #pragma unroll
        for (int i = 0; i < 4; ++i) {
            const int r = wv * 64 + i * 16 + q;        // kout 0..255
            sg[i] = r * W2_ROW + choff;
        }
        ldst = (wid - 4) * 4096;
    }
    const bool is_x = (wid < 4);

    auto issue = [&](int hs, unsigned short* XSb, unsigned short* WSb) {
        const int pos = hs >> 3, k32 = hs & 7;         // hs = pos*8 + k32
        int go; char* dst;
        if (is_x) {
            const int dy = pos / 3, dx = pos - dy * 3;
            go  = (dy - 1) * 4608 + (dx - 1) * 256 + k32 * 32;
            dst = (char*)XSb + ldst;
        } else {
            go  = pos * 256 + k32 * 32;
            dst = (char*)WSb + ldst;
        }
        #pragma unroll
        for (int i = 0; i < 4; ++i)
            gload_lds16(sbase + sg[i] + go, dst + i * 1024);
    };

    // ---- compute setup: wave (wr,wc) owns kout [wr*128,+128) x pix [wc*64,+64)
    const int wr   = wid >> 2, wc = wid & 3;
    const int slot = ((lane >> 1) + (lane >> 4)) & 3;  // (row>>1 + kslot)&3, row-invariant across mt/nt
    const int aoff = (wr * 128 + (lane & 15)) * 32 + slot * 8;
    const int boff = (wc * 64  + (lane & 15)) * 32 + slot * 8;

    const floatx4 z4 = {0.f, 0.f, 0.f, 0.f};
    floatx4 acc[8][4];
    #pragma unroll
    for (int i = 0; i < 8; ++i)
        #pragma unroll
        for (int j = 0; j < 4; ++j) acc[i][j] = z4;

    auto compute = [&](const unsigned short* XSb, const unsigned short* WSb) {
        bf16x8 af[8], bfr[4];
        #pragma unroll
        for (int mt = 0; mt < 8; ++mt)
            af[mt] = *(const bf16x8*)&WSb[aoff + mt * 512];
        #pragma unroll
        for (int nt = 0; nt < 4; ++nt)
            bfr[nt] = *(const bf16x8*)&XSb[boff + nt * 512];
        __builtin_amdgcn_s_setprio(1);
        #pragma unroll
        for (int mt = 0; mt < 8; ++mt)
            #pragma unroll
            for (int nt = 0; nt < 4; ++nt)
                acc[mt][nt] = __builtin_amdgcn_mfma_f32_16x16x32_bf16(
                    af[mt], bfr[nt], acc[mt][nt], 0, 0, 0);
        __builtin_amdgcn_s_setprio(0);
    };

    unsigned short* const xs0 = xs,         * const ws0 = ws;
    unsigned short* const xs1 = xs + 8192,  * const ws1 = ws + 8192;
    unsigned short* const xs2 = xs + 16384, * const ws2 = ws + 16384;
    unsigned short* const xs3 = xs + 24576, * const ws3 = ws + 24576;

    // prologue: 3 batches in flight (4 loads each per wave)
    issue(0, xs0, ws0);
    issue(1, xs1, ws1);
    issue(2, xs2, ws2);

    int hs = 0;
    #pragma unroll 1
    for (int it = 0; it < 17; ++it) {      // computes hs 0..67, issues 3..70
        VMCNT_LGKM0(8); __builtin_amdgcn_s_barrier();
        issue(hs + 3, xs3, ws3);
        compute(xs0, ws0);

        VMCNT_LGKM0(8); __builtin_amdgcn_s_barrier();
        issue(hs + 4, xs0, ws0);
        compute(xs1, ws1);

        VMCNT_LGKM0(8); __builtin_amdgcn_s_barrier();
        issue(hs + 5, xs1, ws1);
        compute(xs2, ws2);

        VMCNT_LGKM0(8); __builtin_amdgcn_s_barrier();
        issue(hs + 6, xs2, ws2);
        compute(xs3, ws3);
        hs += 4;
    }
    // tail: hs = 68..71, drain counts 8 -> 8 -> 4 -> 0
    VMCNT_LGKM0(8); __builtin_amdgcn_s_barrier();
    issue(71, xs3, ws3);
    compute(xs0, ws0);

    VMCNT_LGKM0(8); __builtin_amdgcn_s_barrier();
    compute(xs1, ws1);

    VMCNT_LGKM0(4); __builtin_amdgcn_s_barrier();
    compute(xs2, ws2);

    VMCNT_LGKM0(0); __builtin_amdgcn_s_barrier();
    compute(xs3, ws3);

    // ---- epilogue: C/D 16x16 layout col=lane&15 (pixel), row=(lane>>4)*4+r
    float* ob = out + (size_t)n_img * 65536;
    const int kb = wr * 128 + (lane >> 4) * 4;
    const int pb = wc * 64 + (lane & 15);
    #pragma unroll
    for (int mt = 0; mt < 8; ++mt)
        #pragma unroll
        for (int nt = 0; nt < 4; ++nt) {
            const int kout = kb + mt * 16;
            const int p    = pb + nt * 16;
            #pragma unroll
            for (int r = 0; r < 4; ++r)
                ob[(size_t)(kout + r) * 256 + p] = acc[mt][nt][r];
        }
}

// ---------------------------------------------------------------------------
// Fallback (only if workspace too small for xb): naive conv using w2.
// ---------------------------------------------------------------------------
__global__ __launch_bounds__(256) void naive_conv(
        const float* __restrict__ x, const unsigned short* __restrict__ w2,
        float* __restrict__ out) {
    __shared__ float wr[2304];
    const int n = blockIdx.x >> 8, k = blockIdx.x & 255;
    const int t = threadIdx.x;
    for (int i = t; i < 2304; i += 256)
        wr[i] = __uint_as_float(((unsigned)w2[k * W2_ROW + i]) << 16);
    __syncthreads();
    const int y = t >> 4, xx = t & 15;
    const float* xi = x + (size_t)n * 65536;
    float acc = 0.f;
    for (int pos = 0; pos < 9; ++pos) {
        int dy = pos / 3 - 1, dx = pos % 3 - 1;
        int yy = y + dy, x2 = xx + dx;
        if (yy < 0 || yy > 15 || x2 < 0 || x2 > 15) continue;
        const float* xp = xi + yy * 16 + x2;
        const float* wp = wr + pos * 256;
        for (int c = 0; c < 256; ++c) acc += xp[c * 256] * wp[c];
    }
    out[(size_t)n * 65536 + k * 256 + t] = acc;
}

extern "C" void kernel_launch(void* const* d_in, const int* in_sizes, int n_in,
                              void* d_out, int out_size, void* d_ws, size_t ws_size,
                              hipStream_t stream) {
    const float* x      = (const float*)d_in[0];
    const float* wt     = (const float*)d_in[1];
    const float* alphas = (const float*)d_in[2];
    float* out = (float*)d_out;

    const size_t xb_elems = (size_t)NIMG * XB_IMG;          // 21,233,664
    const size_t w2_elems = (size_t)256 * W2_ROW;           //    589,824
    const size_t need = (xb_elems + w2_elems) * sizeof(unsigned short); // ~43.6 MB

    if (ws_size >= need) {
        unsigned short* xbp = (unsigned short*)d_ws;
        unsigned short* w2p = xbp + xb_elems;
        static bool attr_done = false;
        if (!attr_done) {
            (void)hipFuncSetAttribute(reinterpret_cast<const void*>(&gemm_kernel),
                                      hipFuncAttributeMaxDynamicSharedMemorySize,
                                      131072);
            attr_done = true;
        }
        prep_kernel<<<dim3(1168), 256, 0, stream>>>(x, xbp, wt, alphas, w2p);
        gemm_kernel<<<dim3(256), 512, 131072, stream>>>(xbp, w2p, out);
    } else if (ws_size >= w2_elems * sizeof(unsigned short)) {
        unsigned short* w2p = (unsigned short*)d_ws;
        wprep_kernel<<<dim3(16, 9), 256, 0, stream>>>(wt, alphas, w2p);
        naive_conv<<<dim3(256 * 256), 256, 0, stream>>>(x, w2p, out);
    }
}